// Round 2
// baseline (525.212 us; speedup 1.0000x reference)
//
#include <hip/hip_runtime.h>
#include <hip/hip_bf16.h>

#define Bsz 32
#define Csz 256
#define HWsz 4096
#define NDsz 256
#define Msz 8192   // B*C

typedef __bf16 bf16x8 __attribute__((ext_vector_type(8)));
typedef float  f32x4  __attribute__((ext_vector_type(4)));
typedef short  s16x4  __attribute__((ext_vector_type(4)));
typedef short  s16x8  __attribute__((ext_vector_type(8)));

__device__ __forceinline__ unsigned short f2bf(float f){
  unsigned u = __float_as_uint(f);
  u += 0x7FFFu + ((u >> 16) & 1u);   // RNE; inputs finite
  return (unsigned short)(u >> 16);
}

__device__ __forceinline__ f32x4 mfma16(bf16x8 a, bf16x8 b, f32x4 c){
  return __builtin_amdgcn_mfma_f32_16x16x32_bf16(a, b, c, 0, 0, 0);
}

// ---------------------------------------------------------------------------
// K0: weight transpose + f32->bf16.  Wq/Wk/Wv [4096,256] -> Wt[w][256][4096];
//     Wfc [256,4096] -> Wfct [4096][256].
// ---------------------------------------------------------------------------
__global__ void k_prep(const float* __restrict__ Wq, const float* __restrict__ Wk,
                       const float* __restrict__ Wv, const float* __restrict__ Wfc,
                       unsigned short* __restrict__ Wt, unsigned short* __restrict__ Wfct){
  __shared__ float t[32][33];
  int z = blockIdx.z;
  int bx = blockIdx.x, by = blockIdx.y;       // grid (128, 8, 4)
  const float* src; unsigned short* dst; int R, Ct;
  if (z < 3) {
    src = (z == 0) ? Wq : (z == 1 ? Wk : Wv);
    dst = Wt + (size_t)z * Csz * HWsz;  R = HWsz; Ct = NDsz;
  } else {
    int tidx = bx * 8 + by; bx = tidx & 7; by = tidx >> 3;
    src = Wfc; dst = Wfct; R = NDsz; Ct = HWsz;
  }
  int tx = threadIdx.x, ty = threadIdx.y;     // 32 x 8
  int i0 = bx * 32, j0 = by * 32;
  #pragma unroll
  for (int r = 0; r < 4; r++)
    t[ty + 8*r][tx] = src[(size_t)(i0 + ty + 8*r) * Ct + j0 + tx];
  __syncthreads();
  #pragma unroll
  for (int r = 0; r < 4; r++)
    dst[(size_t)(j0 + ty + 8*r) * R + i0 + tx] = f2bf(t[tx][ty + 8*r]);
}

// ---------------------------------------------------------------------------
// K1: projections.  C[8192,256](bf16) = A[8192,4096](f32) @ Wt[256,4096]^T
// blockIdx.x = which (0=q A=X, 1=k A=X1, 2=v A=X1), blockIdx.y = 64-row tile.
// Tile 64x256, BK=64, 4 waves, wave tile 64x64.
// ---------------------------------------------------------------------------
__global__ __launch_bounds__(256) void k_proj(const float* __restrict__ X,
    const float* __restrict__ X1, const unsigned short* __restrict__ Wt,
    unsigned short* __restrict__ QKV){
  const int which = blockIdx.x;
  const int rt = blockIdx.y;
  const float* A = (which == 0) ? X : X1;
  const unsigned short* Bt = Wt + (size_t)which * NDsz * HWsz;
  unsigned short* Cp = QKV + (size_t)which * Msz * NDsz;

  __shared__ unsigned short As[64][72];    // +8 pad: kills stride-128B bank conflict
  __shared__ unsigned short Bs[256][72];

  const int tid = threadIdx.x;
  const int lane = tid & 63, w = tid >> 6;
  const int l15 = lane & 15, l4 = lane >> 4;

  const int arow = tid >> 2, acol = (tid & 3) * 16;
  const float* agp = A + (size_t)(rt*64 + arow) * HWsz + acol;
  const int brow = tid >> 3, bcol = (tid & 7) * 8;
  const unsigned short* bgp = Bt + (size_t)brow * HWsz + bcol;

  f32x4 acc[4][4] = {};
  float4 ar[4];
  s16x8 br[8];

#define LOADA(kt) { _Pragma("unroll") for (int i = 0; i < 4; i++) \
    ar[i] = *(const float4*)(agp + (size_t)(kt)*64 + i*4); }
#define LOADB(kt) { _Pragma("unroll") for (int p = 0; p < 8; p++) \
    br[p] = *(const s16x8*)(bgp + (size_t)p*32*HWsz + (size_t)(kt)*64); }
#define WRITEAB { _Pragma("unroll") for (int i = 0; i < 4; i++){ s16x4 cv; \
      cv[0]=(short)f2bf(ar[i].x); cv[1]=(short)f2bf(ar[i].y); \
      cv[2]=(short)f2bf(ar[i].z); cv[3]=(short)f2bf(ar[i].w); \
      *(s16x4*)&As[arow][acol + i*4] = cv; } \
    _Pragma("unroll") for (int p = 0; p < 8; p++) *(s16x8*)&Bs[p*32 + brow][bcol] = br[p]; }

  LOADA(0); LOADB(0);
  WRITEAB;
  __syncthreads();

  const int NK = HWsz / 64;
  for (int kt = 1; kt <= NK; kt++){
    const bool more = (kt < NK);
    if (more){ LOADA(kt); LOADB(kt); }   // issue next-tile loads before compute
    #pragma unroll
    for (int kk = 0; kk < 2; kk++){
      bf16x8 a[4], b[4];
      #pragma unroll
      for (int fm = 0; fm < 4; fm++) a[fm] = *(const bf16x8*)&As[fm*16 + l15][kk*32 + l4*8];
      #pragma unroll
      for (int fn = 0; fn < 4; fn++) b[fn] = *(const bf16x8*)&Bs[w*64 + fn*16 + l15][kk*32 + l4*8];
      #pragma unroll
      for (int fm = 0; fm < 4; fm++)
        #pragma unroll
        for (int fn = 0; fn < 4; fn++)
          acc[fm][fn] = mfma16(a[fm], b[fn], acc[fm][fn]);
    }
    if (more){
      __syncthreads();
      WRITEAB;
      __syncthreads();
    }
  }
#undef LOADA
#undef LOADB
#undef WRITEAB
  #pragma unroll
  for (int fm = 0; fm < 4; fm++)
    #pragma unroll
    for (int fn = 0; fn < 4; fn++)
      #pragma unroll
      for (int r = 0; r < 4; r++)
        Cp[(size_t)(rt*64 + fm*16 + l4*4 + r) * NDsz + w*64 + fn*16 + l15] =
            f2bf(acc[fm][fn][r]);
}

// ---------------------------------------------------------------------------
// K2: attention per (b, head).  q,k,v bf16 [8192][256]; out bf16 [8192][256].
// Block = 256 thr (4 waves); wave owns 64 q-rows; loop 4 kv-chunks of 64.
// No max-subtraction (|logit| small enough for f32 exp).
// ---------------------------------------------------------------------------
__global__ __launch_bounds__(256) void k_attn(const unsigned short* __restrict__ Q,
    const unsigned short* __restrict__ K, const unsigned short* __restrict__ V,
    unsigned short* __restrict__ O){
  const int b = blockIdx.x >> 2, n = blockIdx.x & 3;
  __shared__ unsigned short VT[64][264];      // V^T [d][pos], padded
  __shared__ unsigned short PL[4][64][72];    // per-wave P tile, padded

  const int tid = threadIdx.x;
  const int lane = tid & 63, w = tid >> 6;
  const int l15 = lane & 15, l4 = lane >> 4;

  { // stage V^T: VT[d][pos] = V[b*256+pos][n*64+d]
    const unsigned short* vp = V + (size_t)(b*256 + tid) * NDsz + n*64;
    #pragma unroll
    for (int j = 0; j < 8; j++){
      s16x8 vv = *(const s16x8*)(vp + j*8);
      #pragma unroll
      for (int e = 0; e < 8; e++) VT[j*8 + e][tid] = (unsigned short)vv[e];
    }
  }

  bf16x8 qf[4][2];
  #pragma unroll
  for (int fm = 0; fm < 4; fm++)
    #pragma unroll
    for (int ks = 0; ks < 2; ks++)
      qf[fm][ks] = *(const bf16x8*)(Q + (size_t)(b*256 + w*64 + fm*16 + l15) * NDsz
                                      + n*64 + ks*32 + l4*8);

  f32x4 oacc[4][4] = {};
  float rs[4][4] = {};
  __syncthreads();

  for (int ch = 0; ch < 4; ch++){
    f32x4 sacc[4][4] = {};
    #pragma unroll
    for (int ks = 0; ks < 2; ks++){
      bf16x8 kf[4];
      #pragma unroll
      for (int fn = 0; fn < 4; fn++)
        kf[fn] = *(const bf16x8*)(K + (size_t)(b*256 + ch*64 + fn*16 + l15) * NDsz
                                    + n*64 + ks*32 + l4*8);
      #pragma unroll
      for (int fm = 0; fm < 4; fm++)
        #pragma unroll
        for (int fn = 0; fn < 4; fn++)
          sacc[fm][fn] = mfma16(qf[fm][ks], kf[fn], sacc[fm][fn]);
    }
    // exp, row-sum partials, P -> LDS (per-wave buffer; wave-order LDS is safe)
    #pragma unroll
    for (int fm = 0; fm < 4; fm++)
      #pragma unroll
      for (int fn = 0; fn < 4; fn++)
        #pragma unroll
        for (int r = 0; r < 4; r++){
          float e = __expf(sacc[fm][fn][r] * 0.125f);   // /sqrt(64)
          rs[fm][r] += e;
          PL[w][fm*16 + l4*4 + r][fn*16 + l15] = f2bf(e);
        }
    // O += P @ V_chunk
    #pragma unroll
    for (int ks = 0; ks < 2; ks++){
      bf16x8 pa[4], vb[4];
      #pragma unroll
      for (int fm = 0; fm < 4; fm++)
        pa[fm] = *(const bf16x8*)&PL[w][fm*16 + l15][ks*32 + l4*8];
      #pragma unroll
      for (int fn = 0; fn < 4; fn++)
        vb[fn] = *(const bf16x8*)&VT[fn*16 + l15][ch*64 + ks*32 + l4*8];
      #pragma unroll
      for (int fm = 0; fm < 4; fm++)
        #pragma unroll
        for (int fn = 0; fn < 4; fn++)
          oacc[fm][fn] = mfma16(pa[fm], vb[fn], oacc[fm][fn]);
    }
  }
  // reduce row sums over the 16 lanes sharing a row, then normalize+store
  #pragma unroll
  for (int fm = 0; fm < 4; fm++)
    #pragma unroll
    for (int r = 0; r < 4; r++){
      float s = rs[fm][r];
      s += __shfl_xor(s, 1, 16); s += __shfl_xor(s, 2, 16);
      s += __shfl_xor(s, 4, 16); s += __shfl_xor(s, 8, 16);
      rs[fm][r] = 1.0f / s;
    }
  #pragma unroll
  for (int fm = 0; fm < 4; fm++)
    #pragma unroll
    for (int fn = 0; fn < 4; fn++)
      #pragma unroll
      for (int r = 0; r < 4; r++)
        O[(size_t)(b*256 + w*64 + fm*16 + l4*4 + r) * NDsz + n*64 + fn*16 + l15] =
            f2bf(oacc[fm][fn][r] * rs[fm][r]);
}

// ---------------------------------------------------------------------------
// K3: FC.  Y[8192,4096](f32) = AO[8192,256](bf16) @ Wfct[4096,256]^T
// grid (16 col-tiles, 128 row-tiles); epilogue repacks via LDS for float4 stores.
// ---------------------------------------------------------------------------
__global__ __launch_bounds__(256) void k_fc(const unsigned short* __restrict__ AO,
    const unsigned short* __restrict__ Wfct, float* __restrict__ Y){
  const int ct = blockIdx.x, rt = blockIdx.y;
  __shared__ union UU {
    struct { unsigned short As[64][72]; unsigned short Bs[256][72]; } st;
    float Cs[4][64][68];
  } u;
  const int tid = threadIdx.x;
  const int lane = tid & 63, w = tid >> 6;
  const int l15 = lane & 15, l4 = lane >> 4;

  const int arow = tid >> 2, acol = (tid & 3) * 16;
  const unsigned short* agp = AO + (size_t)(rt*64 + arow) * NDsz + acol;
  const int brow = tid >> 3, bcol = (tid & 7) * 8;
  const unsigned short* bgp = Wfct + (size_t)(ct*256 + brow) * NDsz + bcol;

  f32x4 acc[4][4] = {};
  s16x8 ar2[2];
  s16x8 br[8];

#define LOADA(kt) { _Pragma("unroll") for (int i = 0; i < 2; i++) \
    ar2[i] = *(const s16x8*)(agp + (kt)*64 + i*8); }
#define LOADB(kt) { _Pragma("unroll") for (int p = 0; p < 8; p++) \
    br[p] = *(const s16x8*)(bgp + (size_t)p*32*NDsz + (kt)*64); }
#define WRITEAB { _Pragma("unroll") for (int i = 0; i < 2; i++) \
    *(s16x8*)&u.st.As[arow][acol + i*8] = ar2[i]; \
    _Pragma("unroll") for (int p = 0; p < 8; p++) *(s16x8*)&u.st.Bs[p*32 + brow][bcol] = br[p]; }

  LOADA(0); LOADB(0);
  WRITEAB;
  __syncthreads();

  const int NK = NDsz / 64;   // 4
  for (int kt = 1; kt <= NK; kt++){
    const bool more = (kt < NK);
    if (more){ LOADA(kt); LOADB(kt); }
    #pragma unroll
    for (int kk = 0; kk < 2; kk++){
      bf16x8 a[4], b[4];
      #pragma unroll
      for (int fm = 0; fm < 4; fm++) a[fm] = *(const bf16x8*)&u.st.As[fm*16 + l15][kk*32 + l4*8];
      #pragma unroll
      for (int fn = 0; fn < 4; fn++) b[fn] = *(const bf16x8*)&u.st.Bs[w*64 + fn*16 + l15][kk*32 + l4*8];
      #pragma unroll
      for (int fm = 0; fm < 4; fm++)
        #pragma unroll
        for (int fn = 0; fn < 4; fn++)
          acc[fm][fn] = mfma16(a[fm], b[fn], acc[fm][fn]);
    }
    if (more){
      __syncthreads();
      WRITEAB;
      __syncthreads();
    }
  }
#undef LOADA
#undef LOADB
#undef WRITEAB
  __syncthreads();   // all waves done reading staged LDS before union reuse
  #pragma unroll
  for (int fm = 0; fm < 4; fm++)
    #pragma unroll
    for (int fn = 0; fn < 4; fn++)
      #pragma unroll
      for (int r = 0; r < 4; r++)
        u.Cs[w][fm*16 + l4*4 + r][fn*16 + l15] = acc[fm][fn][r];
  #pragma unroll
  for (int i = 0; i < 16; i++){
    int linear = i*64 + lane;
    int row = linear >> 4, f4 = linear & 15;
    float4 v = *(const float4*)&u.Cs[w][row][f4*4];
    *(float4*)(Y + (size_t)(rt*64 + row) * HWsz + ct*256 + w*64 + f4*4) = v;
  }
}

// ---------------------------------------------------------------------------
// K4: per-channel batch stats -> scale/shift.  One block per channel.
// ---------------------------------------------------------------------------
__global__ __launch_bounds__(256) void k_stats(const float* __restrict__ Y,
    const float* __restrict__ gamma, const float* __restrict__ beta,
    float* __restrict__ scale, float* __restrict__ shift){
  const int c = blockIdx.x, t = threadIdx.x;
  float s = 0.f, sq = 0.f;
  for (int b = 0; b < Bsz; b++){
    const float4* p = (const float4*)(Y + (size_t)(b*Csz + c) * HWsz);
    #pragma unroll
    for (int i = 0; i < 4; i++){
      float4 v = p[t + i*256];
      s  += v.x + v.y + v.z + v.w;
      sq += v.x*v.x + v.y*v.y + v.z*v.z + v.w*v.w;
    }
  }
  __shared__ float ls[256], lq[256];
  ls[t] = s; lq[t] = sq;
  __syncthreads();
  for (int o = 128; o > 0; o >>= 1){
    if (t < o){ ls[t] += ls[t+o]; lq[t] += lq[t+o]; }
    __syncthreads();
  }
  if (t == 0){
    const float inv = 1.0f / (float)(Bsz * HWsz);
    float mean = ls[0] * inv;
    float var  = lq[0] * inv - mean*mean;     // biased (ddof=0), matches jnp.var
    float istd = rsqrtf(var + 1e-5f);
    float g = gamma[c] * istd;
    scale[c] = g;
    shift[c] = beta[c] - mean * g;
  }
}

// ---------------------------------------------------------------------------
// K5: in-place BN apply.
// ---------------------------------------------------------------------------
__global__ __launch_bounds__(256) void k_apply(float* __restrict__ Y,
    const float* __restrict__ scale, const float* __restrict__ shift){
  const int NF4 = Msz * HWsz / 4;   // 8388608
  int gstride = gridDim.x * blockDim.x;
  for (int F = blockIdx.x * blockDim.x + threadIdx.x; F < NF4; F += gstride){
    int c = (F >> 10) & 255;        // row = F/1024, c = row % 256
    float4 v = ((const float4*)Y)[F];
    float sc = scale[c], sh = shift[c];
    v.x = v.x*sc + sh; v.y = v.y*sc + sh; v.z = v.z*sc + sh; v.w = v.w*sc + sh;
    ((float4*)Y)[F] = v;
  }
}

// ---------------------------------------------------------------------------
extern "C" void kernel_launch(void* const* d_in, const int* in_sizes, int n_in,
                              void* d_out, int out_size, void* d_ws, size_t ws_size,
                              hipStream_t stream){
  const float* x     = (const float*)d_in[0];
  const float* x1    = (const float*)d_in[1];
  const float* Wq    = (const float*)d_in[2];
  const float* Wk    = (const float*)d_in[3];
  const float* Wv    = (const float*)d_in[4];
  const float* Wfc   = (const float*)d_in[5];
  const float* gamma = (const float*)d_in[6];
  const float* beta  = (const float*)d_in[7];
  float* Y = (float*)d_out;

  unsigned short* Wt   = (unsigned short*)d_ws;                 // 3*256*4096
  unsigned short* Wfct = Wt + (size_t)3*Csz*HWsz;               // 4096*256
  unsigned short* QKV  = Wfct + (size_t)HWsz*NDsz;              // 3*8192*256
  unsigned short* AO   = QKV + (size_t)3*Msz*NDsz;              // 8192*256
  float* scale = (float*)(AO + (size_t)Msz*NDsz);
  float* shift = scale + 256;

  k_prep <<<dim3(128, 8, 4), dim3(32, 8), 0, stream>>>(Wq, Wk, Wv, Wfc, Wt, Wfct);
  k_proj <<<dim3(3, 128),    dim3(256),   0, stream>>>(x, x1, Wt, QKV);
  k_attn <<<dim3(128),       dim3(256),   0, stream>>>(QKV, QKV + (size_t)Msz*NDsz,
                                                       QKV + (size_t)2*Msz*NDsz, AO);
  k_fc   <<<dim3(16, 128),   dim3(256),   0, stream>>>(AO, Wfct, Y);
  k_stats<<<dim3(256),       dim3(256),   0, stream>>>(Y, gamma, beta, scale, shift);
  k_apply<<<dim3(2048),      dim3(256),   0, stream>>>(Y, scale, shift);
}